// Round 17
// baseline (20.252 us; speedup 1.0000x reference)
//
#include <hip/hip_runtime.h>
#include <hip/hip_bf16.h>
#include <math.h>

#define HH 4
#define DD 64
#define BS 32
#define SSEL 4
#define STRIDE (HH * DD)

typedef __attribute__((ext_vector_type(8))) short bf16x8;
typedef __attribute__((ext_vector_type(4))) float f32x4;

__device__ __forceinline__ float silu_f(float x) { return x / (1.0f + __expf(-x)); }

// RNE f32->bf16 pair pack (compiler emits v_cvt_pk_bf16_f32)
__device__ __forceinline__ unsigned int pk2bf(float a, float b) {
    union { __hip_bfloat16 h[2]; unsigned int u; } cu;
    cu.h[0] = __float2bfloat16(a);
    cu.h[1] = __float2bfloat16(b);
    return cu.u;
}

// ---------------------------------------------------------------------------
// Single fused kernel (R14 structure). One WG (8 waves / 512 threads) per
// (query-block, head). Single-tile early issue: step-0 slc loads + QK^T at
// kernel entry (48 regs held), hidden under the means phase. setprio around
// the phase-4 MFMA region (waves are barrier-free + latency-diverse there).
__global__ __launch_bounds__(512, 2) void nsa_all(
        const float* __restrict__ q, const float* __restrict__ k,
        const float* __restrict__ v, const float* __restrict__ gc,
        const float* __restrict__ gs, const int* __restrict__ offs,
        int B, int T, float* __restrict__ out) {
    __shared__ float Qf[32][68];                 // f32 scaled q
    __shared__ float Kc[16][68];                 // f32 block-mean K
    __shared__ float Vc[16][64];                 // f32 block-mean V
    __shared__ unsigned int Msk[32];
    __shared__ unsigned short Qs[32][64];        // bf16, chunk-XOR swizzled
    __shared__ __align__(16) char UN[4 * 32 * 68 * 4];   // Pw (ph4) / Op (ph5/6)

    unsigned int (*Pw)[32][20] = (unsigned int (*)[32][20])UN;
    float        (*Op)[32][68] = (float (*)[32][68])UN;

    int qbh = blockIdx.x;
    int h   = qbh & (HH - 1);
    int qb  = qbh / HH;

    int b = -1, lb = 0, cum = 0, off = 0, n = 0;
    for (int i = 0; i < B; ++i) {
        int o0 = offs[i], o1 = offs[i + 1];
        int nbi = (o1 - o0 + BS - 1) / BS;
        if (qb < cum + nbi) { b = i; lb = qb - cum; off = o0; n = o1 - o0; break; }
        cum += nbi;
    }
    if (b < 0) return;
    int t0  = off + lb * BS;
    int nbl = lb + 1;                // <= 16 (seqlen <= 512)
    const float scale = 0.125f;
    int tid = threadIdx.x;
    int w = tid >> 6, lane = tid & 63;
    int l15 = lane & 15, g = lane >> 4;

    bool have0 = (w <= lb);
    bool have1 = (w + 8 <= lb);

    // ===== EARLY: step-0 tile (kb = w) loads + QK^T; holds only sA+a2A =====
    bf16x8 a2A[4];
    f32x4  sA[2][2];
    if (have0) {
        const float* kbase = k + (size_t)(off + w * BS) * STRIDE + h * DD;
        const float* vbase = v + (size_t)(off + w * BS) * STRIDE + h * DD;

        float tv[4][8];
        #pragma unroll
        for (int dt = 0; dt < 4; ++dt)
            #pragma unroll
            for (int j = 0; j < 8; ++j)
                tv[dt][j] = vbase[(size_t)(g * 8 + j) * STRIDE + dt * 16 + l15];

        float4 kf[2][2][2];
        #pragma unroll
        for (int tt = 0; tt < 2; ++tt)
            #pragma unroll
            for (int ds = 0; ds < 2; ++ds) {
                const float4* p = (const float4*)(kbase + (size_t)(tt * 16 + l15) * STRIDE
                                                  + ds * 32 + g * 8);
                kf[tt][ds][0] = p[0];
                kf[tt][ds][1] = p[1];
            }

        // Q fragments direct from global (same bits as Qs-LDS path)
        bf16x8 b1e[2][2];
        #pragma unroll
        for (int qt = 0; qt < 2; ++qt)
            #pragma unroll
            for (int ds = 0; ds < 2; ++ds) {
                int trow = min(t0 + qt * 16 + l15, T - 1);
                const float4* p = (const float4*)(q + (size_t)trow * STRIDE + h * DD
                                                  + ds * 32 + g * 8);
                float4 x = p[0], y = p[1];
                union { unsigned int u[4]; bf16x8 v8; } cu;
                cu.u[0] = pk2bf(x.x * scale, x.y * scale);
                cu.u[1] = pk2bf(x.z * scale, x.w * scale);
                cu.u[2] = pk2bf(y.x * scale, y.y * scale);
                cu.u[3] = pk2bf(y.z * scale, y.w * scale);
                b1e[qt][ds] = cu.v8;
            }

        bf16x8 a1[2][2];
        #pragma unroll
        for (int tt = 0; tt < 2; ++tt)
            #pragma unroll
            for (int ds = 0; ds < 2; ++ds) {
                union { unsigned int u[4]; bf16x8 v8; } cu;
                float4 x = kf[tt][ds][0], y = kf[tt][ds][1];
                cu.u[0] = pk2bf(x.x, x.y); cu.u[1] = pk2bf(x.z, x.w);
                cu.u[2] = pk2bf(y.x, y.y); cu.u[3] = pk2bf(y.z, y.w);
                a1[tt][ds] = cu.v8;
            }
        #pragma unroll
        for (int dt = 0; dt < 4; ++dt) {
            union { unsigned int u[4]; bf16x8 v8; } cu;
            cu.u[0] = pk2bf(tv[dt][0], tv[dt][1]);
            cu.u[1] = pk2bf(tv[dt][2], tv[dt][3]);
            cu.u[2] = pk2bf(tv[dt][4], tv[dt][5]);
            cu.u[3] = pk2bf(tv[dt][6], tv[dt][7]);
            a2A[dt] = cu.v8;
        }
        #pragma unroll
        for (int kt = 0; kt < 2; ++kt)
            #pragma unroll
            for (int qt = 0; qt < 2; ++qt) {
                sA[kt][qt] = (f32x4){0.f, 0.f, 0.f, 0.f};
                sA[kt][qt] = __builtin_amdgcn_mfma_f32_16x16x32_bf16(a1[kt][0], b1e[qt][0], sA[kt][qt], 0, 0, 0);
                sA[kt][qt] = __builtin_amdgcn_mfma_f32_16x16x32_bf16(a1[kt][1], b1e[qt][1], sA[kt][qt], 0, 0, 0);
            }
    }

    // ---- phase 0a: stage Q (f32 + bf16 swizzled; Qs feeds step-1 b1) ----
    {
        int row = tid >> 4, dg = tid & 15;
        int trow = min(t0 + row, T - 1);
        float4 a = *(const float4*)(q + (size_t)trow * STRIDE + h * DD + dg * 4);
        a.x *= scale; a.y *= scale; a.z *= scale; a.w *= scale;
        *(float4*)&Qf[row][dg * 4] = a;
        uint2 uu = { pk2bf(a.x, a.y), pk2bf(a.z, a.w) };
        *(uint2*)&Qs[row][(((dg >> 1) ^ (row & 7)) * 8) + (dg & 1) * 4] = uu;
    }

    // ---- phase 0b: in-WG block means, one float4 column per thread ----
    if (tid < nbl * 32) {
        int j = tid >> 5, rest = tid & 31, kind = rest >> 4, d4 = rest & 15;
        const float* base = (kind ? v : k) + (size_t)(off + j * BS) * STRIDE + h * DD + d4 * 4;
        float4 acc = {0.f, 0.f, 0.f, 0.f};
        #pragma unroll
        for (int r = 0; r < BS; ++r) {
            float4 x = *(const float4*)(base + (size_t)r * STRIDE);
            acc.x += x.x; acc.y += x.y; acc.z += x.z; acc.w += x.w;
        }
        acc.x *= (1.f / BS); acc.y *= (1.f / BS); acc.z *= (1.f / BS); acc.w *= (1.f / BS);
        if (kind) *(float4*)&Vc[j][d4 * 4] = acc;
        else      *(float4*)&Kc[j][d4 * 4] = acc;
    }
    __syncthreads();

    // ---- phases 1+2+3 fused (barrier-free within 16-lane groups) ----
    {
        int qq = tid >> 4, j = tid & 15;
        int base16 = lane & 48;
        float s = -INFINITY, p = 0.f;
        if (j < nbl) {
            s = 0.f;
            #pragma unroll
            for (int i = 0; i < 16; ++i) {
                float4 qv = *(float4*)&Qf[qq][i * 4];
                float4 kk = *(float4*)&Kc[j][i * 4];
                s += qv.x * kk.x + qv.y * kk.y + qv.z * kk.z + qv.w * kk.w;
            }
            p = silu_f(s);
        }
        int rank = 0;
        #pragma unroll
        for (int i = 0; i < 16; ++i) {
            float si = __shfl(s, base16 | i, 64);
            rank += (si > s) || (si == s && i < j);
        }
        bool sel = (j < nbl) && (rank < SSEL);
        unsigned long long bal = __ballot(sel);
        if (j == 0) Msk[qq] = (unsigned int)((bal >> base16) & 0xFFFFull);

        float4 o = {0.f, 0.f, 0.f, 0.f};
        for (int blk = 0; blk < nbl; ++blk) {
            float pb = __shfl(p, base16 | blk, 64);
            float4 vv = *(float4*)&Vc[blk][j * 4];
            o.x += pb * vv.x; o.y += pb * vv.y; o.z += pb * vv.z; o.w += pb * vv.w;
        }
        if (lb * BS + qq < n) {
            float gv = gc[(size_t)(t0 + qq) * HH + h];
            o.x *= gv; o.y *= gv; o.z *= gv; o.w *= gv;
            *(float4*)(out + (size_t)(t0 + qq) * STRIDE + h * DD + j * 4) = o;
        }
    }
    __syncthreads();

    // ---- phase 4: slc finish; step-0 scores already in regs ----
    unsigned int Msq[2];
    Msq[0] = Msk[l15];
    Msq[1] = Msk[16 + l15];

    f32x4 oacc[4][2];
    #pragma unroll
    for (int dt = 0; dt < 4; ++dt)
        #pragma unroll
        for (int qt = 0; qt < 2; ++qt)
            oacc[dt][qt] = (f32x4){0.f, 0.f, 0.f, 0.f};

#define FINISH(KB, A2, SS)                                                              \
    {                                                                                   \
        const int kb = (KB);                                                            \
        _Pragma("unroll")                                                               \
        for (int kt = 0; kt < 2; ++kt)                                                  \
            _Pragma("unroll")                                                           \
            for (int qt = 0; qt < 2; ++qt) {                                            \
                bool selbit = (Msq[qt] >> kb) & 1u;                                     \
                float pv[4];                                                            \
                _Pragma("unroll")                                                       \
                for (int r = 0; r < 4; ++r) {                                           \
                    int k_l = kt * 16 + g * 4 + r;                                      \
                    int q_l = qt * 16 + l15;                                            \
                    bool ok = selbit && (kb < lb || k_l <= q_l);                        \
                    pv[r] = ok ? silu_f(SS[kt][qt][r]) : 0.f;                           \
                }                                                                       \
                Pw[w][qt * 16 + l15][kt * 8 + g * 2 + 0] = pk2bf(pv[0], pv[1]);         \
                Pw[w][qt * 16 + l15][kt * 8 + g * 2 + 1] = pk2bf(pv[2], pv[3]);         \
            }                                                                           \
        bf16x8 b2[2];                                                                   \
        b2[0] = *(bf16x8*)&Pw[w][l15][g * 4];                                           \
        b2[1] = *(bf16x8*)&Pw[w][16 + l15][g * 4];                                      \
        __builtin_amdgcn_s_setprio(1);                                                  \
        _Pragma("unroll")                                                               \
        for (int dt = 0; dt < 4; ++dt)                                                  \
            _Pragma("unroll")                                                           \
            for (int qt = 0; qt < 2; ++qt)                                              \
                oacc[dt][qt] = __builtin_amdgcn_mfma_f32_16x16x32_bf16(A2[dt], b2[qt], oacc[dt][qt], 0, 0, 0); \
        __builtin_amdgcn_s_setprio(0);                                                  \
    }

    if (have0) FINISH(w, a2A, sA)

    if (have1) {
        const int kb1 = w + 8;
        const float* kbase = k + (size_t)(off + kb1 * BS) * STRIDE + h * DD;
        const float* vbase = v + (size_t)(off + kb1 * BS) * STRIDE + h * DD;

        float tv[4][8];
        #pragma unroll
        for (int dt = 0; dt < 4; ++dt)
            #pragma unroll
            for (int j = 0; j < 8; ++j)
                tv[dt][j] = vbase[(size_t)(g * 8 + j) * STRIDE + dt * 16 + l15];

        float4 kf[2][2][2];
        #pragma unroll
        for (int tt = 0; tt < 2; ++tt)
            #pragma unroll
            for (int ds = 0; ds < 2; ++ds) {
                const float4* p = (const float4*)(kbase + (size_t)(tt * 16 + l15) * STRIDE
                                                  + ds * 32 + g * 8);
                kf[tt][ds][0] = p[0];
                kf[tt][ds][1] = p[1];
            }

        bf16x8 a1[2][2];
        #pragma unroll
        for (int tt = 0; tt < 2; ++tt)
            #pragma unroll
            for (int ds = 0; ds < 2; ++ds) {
                union { unsigned int u[4]; bf16x8 v8; } cu;
                float4 x = kf[tt][ds][0], y = kf[tt][ds][1];
                cu.u[0] = pk2bf(x.x, x.y); cu.u[1] = pk2bf(x.z, x.w);
                cu.u[2] = pk2bf(y.x, y.y); cu.u[3] = pk2bf(y.z, y.w);
                a1[tt][ds] = cu.v8;
            }
        bf16x8 b1[2][2];
        #pragma unroll
        for (int ds = 0; ds < 2; ++ds)
            #pragma unroll
            for (int tt = 0; tt < 2; ++tt)
                b1[tt][ds] = *(bf16x8*)&Qs[tt * 16 + l15][((g + ds * 4) ^ (l15 & 7)) * 8];

        bf16x8 a2B[4];
        #pragma unroll
        for (int dt = 0; dt < 4; ++dt) {
            union { unsigned int u[4]; bf16x8 v8; } cu;
            cu.u[0] = pk2bf(tv[dt][0], tv[dt][1]);
            cu.u[1] = pk2bf(tv[dt][2], tv[dt][3]);
            cu.u[2] = pk2bf(tv[dt][4], tv[dt][5]);
            cu.u[3] = pk2bf(tv[dt][6], tv[dt][7]);
            a2B[dt] = cu.v8;
        }

        f32x4 sB[2][2];
        __builtin_amdgcn_s_setprio(1);
        #pragma unroll
        for (int kt = 0; kt < 2; ++kt)
            #pragma unroll
            for (int qt = 0; qt < 2; ++qt) {
                sB[kt][qt] = (f32x4){0.f, 0.f, 0.f, 0.f};
                sB[kt][qt] = __builtin_amdgcn_mfma_f32_16x16x32_bf16(a1[kt][0], b1[qt][0], sB[kt][qt], 0, 0, 0);
                sB[kt][qt] = __builtin_amdgcn_mfma_f32_16x16x32_bf16(a1[kt][1], b1[qt][1], sB[kt][qt], 0, 0, 0);
            }
        __builtin_amdgcn_s_setprio(0);

        FINISH(kb1, a2B, sB)
    }
#undef FINISH
    __syncthreads();   // all waves done with Pw before Op overlays it

    // ---- phase 5: two-step plane accumulation ----
    if (w < 4) {
        #pragma unroll
        for (int dt = 0; dt < 4; ++dt)
            #pragma unroll
            for (int qt = 0; qt < 2; ++qt)
                #pragma unroll
                for (int r = 0; r < 4; ++r)
                    Op[w][qt * 16 + l15][dt * 16 + g * 4 + r] = oacc[dt][qt][r];
    }
    __syncthreads();
    if (w >= 4) {
        #pragma unroll
        for (int dt = 0; dt < 4; ++dt)
            #pragma unroll
            for (int qt = 0; qt < 2; ++qt)
                #pragma unroll
                for (int r = 0; r < 4; ++r)
                    Op[w - 4][qt * 16 + l15][dt * 16 + g * 4 + r] += oacc[dt][qt][r];
    }
    __syncthreads();

    // ---- phase 6: combine planes, gate, store o_slc ----
    {
        int qq = tid >> 4, dg = tid & 15;
        if (lb * BS + qq < n) {
            float gv = gs[(size_t)(t0 + qq) * HH + h];
            float o[4];
            #pragma unroll
            for (int i = 0; i < 4; ++i) {
                int d = dg * 4 + i;
                o[i] = (Op[0][qq][d] + Op[1][qq][d] + Op[2][qq][d] + Op[3][qq][d]) * gv;
            }
            *(float4*)(out + (size_t)T * STRIDE + (size_t)(t0 + qq) * STRIDE + h * DD + dg * 4)
                = (float4){o[0], o[1], o[2], o[3]};
        }
    }
}

// ---------------------------------------------------------------------------
extern "C" void kernel_launch(void* const* d_in, const int* in_sizes, int n_in,
                              void* d_out, int out_size, void* d_ws, size_t ws_size,
                              hipStream_t stream) {
    const float* q    = (const float*)d_in[0];
    const float* k    = (const float*)d_in[1];
    const float* v    = (const float*)d_in[2];
    const float* gc   = (const float*)d_in[3];
    const float* gs   = (const float*)d_in[4];
    const int*   offs = (const int*)d_in[5];   // JAX x64-off: int32 on device

    int B = in_sizes[5] - 1;
    int T = out_size / (2 * STRIDE);
    int nbcap  = (T + BS - 1) / BS;
    int nqbcap = nbcap + B;                    // upper bound on query blocks

    nsa_all<<<dim3((unsigned)(nqbcap * HH)), dim3(512), 0, stream>>>(
        q, k, v, gc, gs, offs, B, T, (float*)d_out);
}

// Round 18
// 17.594 us; speedup vs baseline: 1.1510x; 1.1510x over previous
//
#include <hip/hip_runtime.h>
#include <hip/hip_bf16.h>
#include <math.h>

#define HH 4
#define DD 64
#define BS 32
#define SSEL 4
#define STRIDE (HH * DD)

typedef __attribute__((ext_vector_type(8))) short bf16x8;
typedef __attribute__((ext_vector_type(4))) float f32x4;

__device__ __forceinline__ float silu_f(float x) { return x / (1.0f + __expf(-x)); }

// RNE f32->bf16 pair pack (compiler emits v_cvt_pk_bf16_f32)
__device__ __forceinline__ unsigned int pk2bf(float a, float b) {
    union { __hip_bfloat16 h[2]; unsigned int u; } cu;
    cu.h[0] = __float2bfloat16(a);
    cu.h[1] = __float2bfloat16(b);
    return cu.u;
}

// ---------------------------------------------------------------------------
// Single fused kernel (R14 — measured optimum, 17.62 us). One WG (8 waves /
// 512 threads) per (query-block, head). Phases 1-3 fused barrier-free via
// 16-lane shuffles; low-pressure slc engine (loads at step head, no
// cross-phase prefetch — every prefetch variant measured slower).
__global__ __launch_bounds__(512, 2) void nsa_all(
        const float* __restrict__ q, const float* __restrict__ k,
        const float* __restrict__ v, const float* __restrict__ gc,
        const float* __restrict__ gs, const int* __restrict__ offs,
        int B, int T, float* __restrict__ out) {
    __shared__ float Qf[32][68];                 // f32 scaled q
    __shared__ float Kc[16][68];                 // f32 block-mean K
    __shared__ float Vc[16][64];                 // f32 block-mean V
    __shared__ unsigned int Msk[32];
    __shared__ unsigned short Qs[32][64];        // bf16, chunk-XOR swizzled
    __shared__ __align__(16) char UN[4 * 32 * 68 * 4];   // Pw (ph4) / Op (ph5/6)

    unsigned int (*Pw)[32][20] = (unsigned int (*)[32][20])UN;
    float        (*Op)[32][68] = (float (*)[32][68])UN;

    int qbh = blockIdx.x;
    int h   = qbh & (HH - 1);
    int qb  = qbh / HH;

    int b = -1, lb = 0, cum = 0, off = 0, n = 0;
    for (int i = 0; i < B; ++i) {
        int o0 = offs[i], o1 = offs[i + 1];
        int nbi = (o1 - o0 + BS - 1) / BS;
        if (qb < cum + nbi) { b = i; lb = qb - cum; off = o0; n = o1 - o0; break; }
        cum += nbi;
    }
    if (b < 0) return;
    int t0  = off + lb * BS;
    int nbl = lb + 1;                // <= 16 (seqlen <= 512)
    const float scale = 0.125f;
    int tid = threadIdx.x;
    int w = tid >> 6, lane = tid & 63;
    int l15 = lane & 15, g = lane >> 4;

    // ---- phase 0a: stage Q (f32 + bf16 swizzled) ----
    {
        int row = tid >> 4, dg = tid & 15;
        int trow = min(t0 + row, T - 1);
        float4 a = *(const float4*)(q + (size_t)trow * STRIDE + h * DD + dg * 4);
        a.x *= scale; a.y *= scale; a.z *= scale; a.w *= scale;
        *(float4*)&Qf[row][dg * 4] = a;
        uint2 uu = { pk2bf(a.x, a.y), pk2bf(a.z, a.w) };
        *(uint2*)&Qs[row][(((dg >> 1) ^ (row & 7)) * 8) + (dg & 1) * 4] = uu;
    }

    // ---- phase 0b: in-WG block means, one float4 column per thread ----
    if (tid < nbl * 32) {
        int j = tid >> 5, rest = tid & 31, kind = rest >> 4, d4 = rest & 15;
        const float* base = (kind ? v : k) + (size_t)(off + j * BS) * STRIDE + h * DD + d4 * 4;
        float4 acc = {0.f, 0.f, 0.f, 0.f};
        #pragma unroll
        for (int r = 0; r < BS; ++r) {
            float4 x = *(const float4*)(base + (size_t)r * STRIDE);
            acc.x += x.x; acc.y += x.y; acc.z += x.z; acc.w += x.w;
        }
        acc.x *= (1.f / BS); acc.y *= (1.f / BS); acc.z *= (1.f / BS); acc.w *= (1.f / BS);
        if (kind) *(float4*)&Vc[j][d4 * 4] = acc;
        else      *(float4*)&Kc[j][d4 * 4] = acc;
    }
    __syncthreads();

    // ---- phases 1+2+3 fused (barrier-free within 16-lane groups) ----
    // thread (qq = tid>>4, j = tid&15): score, rank, silu, PV all via shfl.
    {
        int qq = tid >> 4, j = tid & 15;
        int base16 = lane & 48;
        float s = -INFINITY, p = 0.f;
        if (j < nbl) {
            s = 0.f;
            #pragma unroll
            for (int i = 0; i < 16; ++i) {
                float4 qv = *(float4*)&Qf[qq][i * 4];
                float4 kk = *(float4*)&Kc[j][i * 4];
                s += qv.x * kk.x + qv.y * kk.y + qv.z * kk.z + qv.w * kk.w;
            }
            p = silu_f(s);
        }
        // rank among the 16 group scores (strict >, lower idx wins ties)
        int rank = 0;
        #pragma unroll
        for (int i = 0; i < 16; ++i) {
            float si = __shfl(s, base16 | i, 64);
            rank += (si > s) || (si == s && i < j);
        }
        bool sel = (j < nbl) && (rank < SSEL);
        unsigned long long bal = __ballot(sel);
        if (j == 0) Msk[qq] = (unsigned int)((bal >> base16) & 0xFFFFull);

        // cmp PV: thread (qq, dg=j), p broadcast from group lane blk
        float4 o = {0.f, 0.f, 0.f, 0.f};
        for (int blk = 0; blk < nbl; ++blk) {
            float pb = __shfl(p, base16 | blk, 64);
            float4 vv = *(float4*)&Vc[blk][j * 4];
            o.x += pb * vv.x; o.y += pb * vv.y; o.z += pb * vv.z; o.w += pb * vv.w;
        }
        if (lb * BS + qq < n) {
            float gv = gc[(size_t)(t0 + qq) * HH + h];
            o.x *= gv; o.y *= gv; o.z *= gv; o.w *= gv;
            *(float4*)(out + (size_t)(t0 + qq) * STRIDE + h * DD + j * 4) = o;
        }
    }
    __syncthreads();

    // ---- phase 4: slc attention via MFMA; loads at step head, low pressure ----
    unsigned int Msq[2];
    Msq[0] = Msk[l15];
    Msq[1] = Msk[16 + l15];

    f32x4 oacc[4][2];
    #pragma unroll
    for (int dt = 0; dt < 4; ++dt)
        #pragma unroll
        for (int qt = 0; qt < 2; ++qt)
            oacc[dt][qt] = (f32x4){0.f, 0.f, 0.f, 0.f};

    #pragma unroll 1
    for (int kb = w; kb <= lb; kb += 8) {
        const float* kbase = k + (size_t)(off + kb * BS) * STRIDE + h * DD;
        const float* vbase = v + (size_t)(off + kb * BS) * STRIDE + h * DD;

        // V^T gather first (32 scalar L2 loads -> overlap with K loads below)
        float tv[4][8];
        #pragma unroll
        for (int dt = 0; dt < 4; ++dt)
            #pragma unroll
            for (int j = 0; j < 8; ++j)
                tv[dt][j] = vbase[(size_t)(g * 8 + j) * STRIDE + dt * 16 + l15];

        // K fragments direct from global: a1[tt][ds] = K[tt*16+l15][ds*32+g*8 ..+7]
        float4 kf[2][2][2];
        #pragma unroll
        for (int tt = 0; tt < 2; ++tt)
            #pragma unroll
            for (int ds = 0; ds < 2; ++ds) {
                const float4* p = (const float4*)(kbase + (size_t)(tt * 16 + l15) * STRIDE
                                                  + ds * 32 + g * 8);
                kf[tt][ds][0] = p[0];
                kf[tt][ds][1] = p[1];
            }

        bf16x8 a1[2][2];
        #pragma unroll
        for (int tt = 0; tt < 2; ++tt)
            #pragma unroll
            for (int ds = 0; ds < 2; ++ds) {
                union { unsigned int u[4]; bf16x8 v8; } cu;
                float4 x = kf[tt][ds][0], y = kf[tt][ds][1];
                cu.u[0] = pk2bf(x.x, x.y); cu.u[1] = pk2bf(x.z, x.w);
                cu.u[2] = pk2bf(y.x, y.y); cu.u[3] = pk2bf(y.z, y.w);
                a1[tt][ds] = cu.v8;
            }
        bf16x8 b1[2][2];
        #pragma unroll
        for (int ds = 0; ds < 2; ++ds)
            #pragma unroll
            for (int tt = 0; tt < 2; ++tt)
                b1[tt][ds] = *(bf16x8*)&Qs[tt * 16 + l15][((g + ds * 4) ^ (l15 & 7)) * 8];

        f32x4 s[2][2];
        #pragma unroll
        for (int kt = 0; kt < 2; ++kt)
            #pragma unroll
            for (int qt = 0; qt < 2; ++qt) {
                s[kt][qt] = (f32x4){0.f, 0.f, 0.f, 0.f};
                s[kt][qt] = __builtin_amdgcn_mfma_f32_16x16x32_bf16(a1[kt][0], b1[qt][0], s[kt][qt], 0, 0, 0);
                s[kt][qt] = __builtin_amdgcn_mfma_f32_16x16x32_bf16(a1[kt][1], b1[qt][1], s[kt][qt], 0, 0, 0);
            }

        // mask + silu + pack P (bf16) via wave-private LDS (layout shuffle)
        #pragma unroll
        for (int kt = 0; kt < 2; ++kt)
            #pragma unroll
            for (int qt = 0; qt < 2; ++qt) {
                bool selbit = (Msq[qt] >> kb) & 1u;
                float pv[4];
                #pragma unroll
                for (int r = 0; r < 4; ++r) {
                    int k_l = kt * 16 + g * 4 + r;
                    int q_l = qt * 16 + l15;
                    bool ok = selbit && (kb < lb || k_l <= q_l);
                    pv[r] = ok ? silu_f(s[kt][qt][r]) : 0.f;
                }
                Pw[w][qt * 16 + l15][kt * 8 + g * 2 + 0] = pk2bf(pv[0], pv[1]);
                Pw[w][qt * 16 + l15][kt * 8 + g * 2 + 1] = pk2bf(pv[2], pv[3]);
            }
        bf16x8 b2[2];
        b2[0] = *(bf16x8*)&Pw[w][l15][g * 4];
        b2[1] = *(bf16x8*)&Pw[w][16 + l15][g * 4];

        bf16x8 a2[4];
        #pragma unroll
        for (int dt = 0; dt < 4; ++dt) {
            union { unsigned int u[4]; bf16x8 v8; } cu;
            cu.u[0] = pk2bf(tv[dt][0], tv[dt][1]);
            cu.u[1] = pk2bf(tv[dt][2], tv[dt][3]);
            cu.u[2] = pk2bf(tv[dt][4], tv[dt][5]);
            cu.u[3] = pk2bf(tv[dt][6], tv[dt][7]);
            a2[dt] = cu.v8;
        }

        #pragma unroll
        for (int dt = 0; dt < 4; ++dt)
            #pragma unroll
            for (int qt = 0; qt < 2; ++qt)
                oacc[dt][qt] = __builtin_amdgcn_mfma_f32_16x16x32_bf16(a2[dt], b2[qt], oacc[dt][qt], 0, 0, 0);
    }
    __syncthreads();   // all waves done with Pw before Op overlays it

    // ---- phase 5: two-step plane accumulation ----
    if (w < 4) {
        #pragma unroll
        for (int dt = 0; dt < 4; ++dt)
            #pragma unroll
            for (int qt = 0; qt < 2; ++qt)
                #pragma unroll
                for (int r = 0; r < 4; ++r)
                    Op[w][qt * 16 + l15][dt * 16 + g * 4 + r] = oacc[dt][qt][r];
    }
    __syncthreads();
    if (w >= 4) {
        #pragma unroll
        for (int dt = 0; dt < 4; ++dt)
            #pragma unroll
            for (int qt = 0; qt < 2; ++qt)
                #pragma unroll
                for (int r = 0; r < 4; ++r)
                    Op[w - 4][qt * 16 + l15][dt * 16 + g * 4 + r] += oacc[dt][qt][r];
    }
    __syncthreads();

    // ---- phase 6: combine planes, gate, store o_slc ----
    {
        int qq = tid >> 4, dg = tid & 15;
        if (lb * BS + qq < n) {
            float gv = gs[(size_t)(t0 + qq) * HH + h];
            float o[4];
            #pragma unroll
            for (int i = 0; i < 4; ++i) {
                int d = dg * 4 + i;
                o[i] = (Op[0][qq][d] + Op[1][qq][d] + Op[2][qq][d] + Op[3][qq][d]) * gv;
            }
            *(float4*)(out + (size_t)T * STRIDE + (size_t)(t0 + qq) * STRIDE + h * DD + dg * 4)
                = (float4){o[0], o[1], o[2], o[3]};
        }
    }
}

// ---------------------------------------------------------------------------
extern "C" void kernel_launch(void* const* d_in, const int* in_sizes, int n_in,
                              void* d_out, int out_size, void* d_ws, size_t ws_size,
                              hipStream_t stream) {
    const float* q    = (const float*)d_in[0];
    const float* k    = (const float*)d_in[1];
    const float* v    = (const float*)d_in[2];
    const float* gc   = (const float*)d_in[3];
    const float* gs   = (const float*)d_in[4];
    const int*   offs = (const int*)d_in[5];   // JAX x64-off: int32 on device

    int B = in_sizes[5] - 1;
    int T = out_size / (2 * STRIDE);
    int nbcap  = (T + BS - 1) / BS;
    int nqbcap = nbcap + B;                    // upper bound on query blocks

    nsa_all<<<dim3((unsigned)(nqbcap * HH)), dim3(512), 0, stream>>>(
        q, k, v, gc, gs, offs, B, T, (float*)d_out);
}